// Round 7
// baseline (408.570 us; speedup 1.0000x reference)
//
#include <hip/hip_runtime.h>
#include <float.h>
#include <math.h>

#define Bc 512
#define Sc 100
#define Hc 1024
#define Ac 128
#define Nc 8
#define AS_ST 68
#define BS_ST 132

// ---------------- K0a: positional-encoding table pe[S][H] ----------------
__global__ __launch_bounds__(256) void pe_kernel(float* __restrict__ pe){
  int s = blockIdx.x;
  int t = threadIdx.x;
  const float fac = (float)(-9.210340371976184 / 1024.0);  // -ln(10000)/H
  for(int i = t; i < Hc/2; i += 256){
    float div = expf((float)(2*i) * fac);
    float a = (float)s * div;
    pe[s*Hc + 2*i]     = sinf(a);
    pe[s*Hc + 2*i + 1] = cosf(a);
  }
}

// ---------------- K0b: pesum[h] = sum_s pe[s][h] ----------------
__global__ __launch_bounds__(256) void pesum_kernel(const float* __restrict__ pe, float* __restrict__ pesum){
  int h = blockIdx.x*256 + threadIdx.x;
  float acc = 0.f;
  for(int s = 0; s < Sc; ++s) acc += pe[s*Hc + h];
  pesum[h] = acc;
}

// ---------------- K1: xsp[b][q][h] = sum_{s in quarter q} x[b,s,h]  (+pesum at q==0) ----------------
__global__ __launch_bounds__(256) void xsum_kernel(const float* __restrict__ x, const float* __restrict__ pesum,
                                                   float* __restrict__ xsp){
  int b = blockIdx.x;
  int q = blockIdx.y;
  int t = threadIdx.x;
  const float4* xr = (const float4*)(x + (size_t)b*Sc*Hc);
  float4 acc;
  if(q == 0) acc = ((const float4*)pesum)[t];
  else       acc = make_float4(0.f,0.f,0.f,0.f);
  int s0 = q*25;
  #pragma unroll 5
  for(int s = s0; s < s0+25; ++s){
    float4 v = xr[s*(Hc/4) + t];
    acc.x += v.x; acc.y += v.y; acc.z += v.z; acc.w += v.w;
  }
  ((float4*)(xsp + ((size_t)b*4 + q)*Hc))[t] = acc;
}

// ---------------- K1b: xs[b][h] = sum_q xsp[b][q][h] ----------------
__global__ __launch_bounds__(256) void xsred_kernel(const float* __restrict__ xsp, float* __restrict__ xs){
  int b = blockIdx.x, t = threadIdx.x;
  const float4* p = (const float4*)(xsp + (size_t)b*4*Hc);
  float4 a = p[t], b1 = p[256+t], c = p[512+t], d = p[768+t];
  a.x += b1.x + c.x + d.x;
  a.y += b1.y + c.y + d.y;
  a.z += b1.z + c.z + d.z;
  a.w += b1.w + c.w + d.w;
  ((float4*)(xs + (size_t)b*Hc))[t] = a;
}

// ---------------- K2: Ksum4[ks][b][j] = sum_{k in slice ks} xs[b][k] * Wk[j][k] ----------------
__global__ __launch_bounds__(256) void ksum_gemm2(const float* __restrict__ xs, const float* __restrict__ Wk,
                                                  float* __restrict__ Ksum4){
  __shared__ float As[32*AS_ST];   // [kk][m]  8.7 KB
  __shared__ float Bs[32*BS_ST];   // [kk][j] 16.9 KB
  const int t = threadIdx.x;
  const int j0 = blockIdx.x*128, b0 = blockIdx.y*64, ks = blockIdx.z;
  const int ty = t>>4, tx = t&15;
  float acc[4][8];
  #pragma unroll
  for(int i = 0; i < 4; ++i)
    #pragma unroll
    for(int j = 0; j < 8; ++j) acc[i][j] = 0.f;

  for(int k0 = ks*256; k0 < ks*256 + 256; k0 += 32){
    float4 af[2], bf[4];
    #pragma unroll
    for(int i = 0; i < 2; ++i){
      int id = t + i*256; int m = id>>3, q = id&7;
      af[i] = *(const float4*)(xs + ((size_t)(b0+m)<<10) + k0 + q*4);
    }
    #pragma unroll
    for(int i = 0; i < 4; ++i){
      int id = t + i*256; int r = id>>3, c = id&7;
      bf[i] = *(const float4*)(Wk + ((size_t)(j0+r)<<10) + k0 + c*4);
    }
    __syncthreads();
    #pragma unroll
    for(int i = 0; i < 2; ++i){
      int id = t + i*256; int m = id>>3, q = id&7;
      As[(q*4+0)*AS_ST + m] = af[i].x;
      As[(q*4+1)*AS_ST + m] = af[i].y;
      As[(q*4+2)*AS_ST + m] = af[i].z;
      As[(q*4+3)*AS_ST + m] = af[i].w;
    }
    #pragma unroll
    for(int i = 0; i < 4; ++i){
      int id = t + i*256; int r = id>>3, c = id&7;
      Bs[(c*4+0)*BS_ST + r] = bf[i].x;
      Bs[(c*4+1)*BS_ST + r] = bf[i].y;
      Bs[(c*4+2)*BS_ST + r] = bf[i].z;
      Bs[(c*4+3)*BS_ST + r] = bf[i].w;
    }
    __syncthreads();
    #pragma unroll 8
    for(int kk = 0; kk < 32; ++kk){
      float4 a4 = *(const float4*)&As[kk*AS_ST + ty*4];
      float4 bu = *(const float4*)&Bs[kk*BS_ST + tx*4];
      float4 bv = *(const float4*)&Bs[kk*BS_ST + 64 + tx*4];
      float a[4] = {a4.x, a4.y, a4.z, a4.w};
      float bb[8] = {bu.x,bu.y,bu.z,bu.w, bv.x,bv.y,bv.z,bv.w};
      #pragma unroll
      for(int i = 0; i < 4; ++i)
        #pragma unroll
        for(int j = 0; j < 8; ++j)
          acc[i][j] = fmaf(a[i], bb[j], acc[i][j]);
    }
  }
  #pragma unroll
  for(int i = 0; i < 4; ++i){
    float* cp = Ksum4 + (((size_t)ks*Bc + b0 + ty*4 + i)<<10) + j0 + tx*4;
    *(float4*)cp        = make_float4(acc[i][0],acc[i][1],acc[i][2],acc[i][3]);
    *(float4*)(cp + 64) = make_float4(acc[i][4],acc[i][5],acc[i][6],acc[i][7]);
  }
}

// ---------------- K2b: Ksum[b][j] = sum_ks Ksum4[ks][b][j] ----------------
__global__ __launch_bounds__(256) void ksred_kernel(const float* __restrict__ Ksum4, float* __restrict__ Ksum){
  int b = blockIdx.x, t = threadIdx.x;
  const float4* p = (const float4*)(Ksum4 + ((size_t)b<<10));
  const size_t sl = (size_t)Bc*Hc/4;
  float4 a = p[t], b1 = p[sl+t], c = p[2*sl+t], d = p[3*sl+t];
  a.x += b1.x + c.x + d.x;
  a.y += b1.y + c.y + d.y;
  a.z += b1.z + c.z + d.z;
  a.w += b1.w + c.w + d.w;
  ((float4*)(Ksum + ((size_t)b<<10)))[t] = a;
}

// ---------------- K3: v[b][n][h] = sum_a Ksum[b][n*A+a] * Wq[n*A+a][h] ----------------
__global__ __launch_bounds__(256) void v_gemm2(const float* __restrict__ Ksum, const float* __restrict__ Wq,
                                               float* __restrict__ v){
  __shared__ float As[32*AS_ST];
  __shared__ float Bs[32*BS_ST];
  const int t = threadIdx.x;
  const int h0 = blockIdx.x*128, b0 = blockIdx.y*64, n = blockIdx.z;
  const int ty = t>>4, tx = t&15;
  float acc[4][8];
  #pragma unroll
  for(int i = 0; i < 4; ++i)
    #pragma unroll
    for(int j = 0; j < 8; ++j) acc[i][j] = 0.f;

  for(int k0 = 0; k0 < Ac; k0 += 32){
    float4 af[2], bf[4];
    #pragma unroll
    for(int i = 0; i < 2; ++i){
      int id = t + i*256; int m = id>>3, q = id&7;
      af[i] = *(const float4*)(Ksum + ((size_t)(b0+m)<<10) + n*Ac + k0 + q*4);
    }
    #pragma unroll
    for(int i = 0; i < 4; ++i){
      int id = t + i*256; int kk = id>>5, q = id&31;
      bf[i] = *(const float4*)(Wq + ((size_t)(n*Ac + k0 + kk)<<10) + h0 + q*4);
    }
    __syncthreads();
    #pragma unroll
    for(int i = 0; i < 2; ++i){
      int id = t + i*256; int m = id>>3, q = id&7;
      As[(q*4+0)*AS_ST + m] = af[i].x;
      As[(q*4+1)*AS_ST + m] = af[i].y;
      As[(q*4+2)*AS_ST + m] = af[i].z;
      As[(q*4+3)*AS_ST + m] = af[i].w;
    }
    #pragma unroll
    for(int i = 0; i < 4; ++i){
      int id = t + i*256; int kk = id>>5, q = id&31;
      *(float4*)&Bs[kk*BS_ST + q*4] = bf[i];
    }
    __syncthreads();
    #pragma unroll 8
    for(int kk = 0; kk < 32; ++kk){
      float4 a4 = *(const float4*)&As[kk*AS_ST + ty*4];
      float4 bu = *(const float4*)&Bs[kk*BS_ST + tx*4];
      float4 bv = *(const float4*)&Bs[kk*BS_ST + 64 + tx*4];
      float a[4] = {a4.x, a4.y, a4.z, a4.w};
      float bb[8] = {bu.x,bu.y,bu.z,bu.w, bv.x,bv.y,bv.z,bv.w};
      #pragma unroll
      for(int i = 0; i < 4; ++i)
        #pragma unroll
        for(int j = 0; j < 8; ++j)
          acc[i][j] = fmaf(a[i], bb[j], acc[i][j]);
    }
  }
  #pragma unroll
  for(int i = 0; i < 4; ++i){
    float* cp = v + (((size_t)(b0 + ty*4 + i)*Nc + n)<<10) + h0 + tx*4;
    *(float4*)cp        = make_float4(acc[i][0],acc[i][1],acc[i][2],acc[i][3]);
    *(float4*)(cp + 64) = make_float4(acc[i][4],acc[i][5],acc[i][6],acc[i][7]);
  }
}

// ---------------- K4: x.v logits -> +gumbel -> argmax_s -> gather rows of x ----------------
// One block (1024 thr = 16 waves) per b. v[b] (32KB) held in REGISTERS: 32 float4/lane,
// loaded once. Lanes->k: x/pe reads directly coalesced, NO LDS tile, NO barriers in the
// hot loop, no redundant v traffic. Per s: 8 loads + 144 FMA + 34-op butterfly reduce.
__global__ __launch_bounds__(1024, 8) void attn_kernel(const float* __restrict__ x, const float* __restrict__ pe,
                                                       const float* __restrict__ v, const float* __restrict__ g,
                                                       float* __restrict__ out){
  __shared__ float lg[Sc][9];          // logits [s][n], pad 9 (coprime 32) -> <=2-way reads
  __shared__ int sidx[Nc];
  const int b = blockIdx.x;
  const int t = threadIdx.x;
  const int lane = t & 63;
  const int w = t >> 6;                // wave 0..15

  // resident v: vr[n][i] = v[b,n, lane*? ] -> lane covers k = (i*64+lane)*4 .. +3
  const float4* vb4 = (const float4*)(v + (size_t)b*Nc*Hc);
  float4 vr[Nc][4];
  #pragma unroll
  for(int n = 0; n < Nc; ++n)
    #pragma unroll
    for(int i = 0; i < 4; ++i)
      vr[n][i] = vb4[n*256 + i*64 + lane];

  const float4* xb4 = (const float4*)(x + (size_t)b*Sc*Hc);
  const float4* pe4 = (const float4*)pe;

  for(int s = w; s < Sc; s += 16){
    float4 e[4];
    #pragma unroll
    for(int i = 0; i < 4; ++i){
      float4 xv = xb4[s*256 + i*64 + lane];
      float4 pv = pe4[s*256 + i*64 + lane];
      e[i] = make_float4(xv.x+pv.x, xv.y+pv.y, xv.z+pv.z, xv.w+pv.w);
    }
    float acc[Nc];
    #pragma unroll
    for(int n = 0; n < Nc; ++n){
      float a = 0.f;
      #pragma unroll
      for(int i = 0; i < 4; ++i){
        a = fmaf(e[i].x, vr[n][i].x, a);
        a = fmaf(e[i].y, vr[n][i].y, a);
        a = fmaf(e[i].z, vr[n][i].z, a);
        a = fmaf(e[i].w, vr[n][i].w, a);
      }
      acc[n] = a;
    }
    // stage A: butterfly within 8-lane groups, all 8 heads (24 shfl)
    #pragma unroll
    for(int m = 1; m <= 4; m <<= 1)
      #pragma unroll
      for(int n = 0; n < Nc; ++n)
        acc[n] += __shfl_xor(acc[n], m, 64);
    // select head n = lane&7 (7 cndmask, compile-time unrolled)
    float keep = acc[0];
    #pragma unroll
    for(int n = 1; n < Nc; ++n)
      keep = ((lane & 7) == n) ? acc[n] : keep;
    // stage B: butterfly across groups (3 shfl)
    #pragma unroll
    for(int m = 8; m <= 32; m <<= 1)
      keep += __shfl_xor(keep, m, 64);
    if(lane < Nc) lg[s][lane] = keep;   // lane L holds full sum for head L
  }
  __syncthreads();

  // phase 2: y = lg/3200 + gumbel; argmax over s. Waves 0..7, one head each.
  if(w < Nc){
    int n = w, j = lane;
    float best = -FLT_MAX; int bidx = 0;
    #pragma unroll
    for(int i = 0; i < 2; ++i){
      int s2 = j + 64*i;
      if(s2 < Sc){
        float y = lg[s2][n]/3200.0f + g[(size_t)(b*Nc + n)*Sc + s2];
        if(y > best){ best = y; bidx = s2; }   // strict > keeps first index (jnp tie rule)
      }
    }
    #pragma unroll
    for(int m = 32; m >= 1; m >>= 1){
      float ob = __shfl_xor(best, m, 64);
      int   oi = __shfl_xor(bidx, m, 64);
      if(ob > best || (ob == best && oi < bidx)){ best = ob; bidx = oi; }
    }
    if(j == 0) sidx[n] = bidx;
  }
  __syncthreads();

  // phase 3: out[b,n,:] = x[b, s*, :]  (2048 float4 over 1024 threads)
  float4* ob4 = (float4*)(out + (size_t)b*Nc*Hc);
  #pragma unroll
  for(int i = 0; i < 2; ++i){
    int idx = i*1024 + t;
    int nn = idx >> 8, c = idx & 255;
    ob4[idx] = xb4[sidx[nn]*256 + c];
  }
}

extern "C" void kernel_launch(void* const* d_in, const int* in_sizes, int n_in,
                              void* d_out, int out_size, void* d_ws, size_t ws_size,
                              hipStream_t stream) {
  const float* x  = (const float*)d_in[0];   // [512,100,1024]
  const float* Wq = (const float*)d_in[1];   // [1024,1024]
  const float* Wk = (const float*)d_in[2];   // [1024,1024]
  const float* g  = (const float*)d_in[3];   // [4096,100]
  float* out = (float*)d_out;                // [512,8,1024]

  char* ws = (char*)d_ws;
  float* pe    = (float*)(ws);                //    409,600 B
  float* pesum = (float*)(ws +    409600);    //      4,096 B
  float* xsp   = (float*)(ws +    413696);    //  8,388,608 B  [512][4][1024]
  float* Ksum4 = (float*)(ws +    413696);    //  aliases xsp (dead after xsred) [4][512][1024]
  float* xs    = (float*)(ws +   8802304);    //  2,097,152 B  [512][1024]
  float* Ksum  = (float*)(ws +  10899456);    //  2,097,152 B  [512][1024]
  float* v     = (float*)(ws +  12996608);    // 16,777,216 B  (total ~29.8 MB)

  pe_kernel   <<<100, 256, 0, stream>>>(pe);
  pesum_kernel<<<4,   256, 0, stream>>>(pe, pesum);
  xsum_kernel <<<dim3(512,4), 256, 0, stream>>>(x, pesum, xsp);
  xsred_kernel<<<512, 256, 0, stream>>>(xsp, xs);
  ksum_gemm2  <<<dim3(8,8,4), 256, 0, stream>>>(xs, Wk, Ksum4);
  ksred_kernel<<<512, 256, 0, stream>>>(Ksum4, Ksum);
  v_gemm2     <<<dim3(8,8,8), 256, 0, stream>>>(Ksum, Wq, v);
  attn_kernel <<<512, 1024, 0, stream>>>(x, pe, v, g, out);
}

// Round 8
// 153.109 us; speedup vs baseline: 2.6685x; 2.6685x over previous
//
#include <hip/hip_runtime.h>
#include <float.h>
#include <math.h>

#define Bc 512
#define Sc 100
#define Hc 1024
#define Ac 128
#define Nc 8
#define AS_ST 68
#define BS_ST 132

// ---------------- K0a: positional-encoding table pe[S][H] ----------------
__global__ __launch_bounds__(256) void pe_kernel(float* __restrict__ pe){
  int s = blockIdx.x;
  int t = threadIdx.x;
  const float fac = (float)(-9.210340371976184 / 1024.0);  // -ln(10000)/H
  for(int i = t; i < Hc/2; i += 256){
    float div = expf((float)(2*i) * fac);
    float a = (float)s * div;
    pe[s*Hc + 2*i]     = sinf(a);
    pe[s*Hc + 2*i + 1] = cosf(a);
  }
}

// ---------------- K0b: pesum[h] = sum_s pe[s][h] ----------------
__global__ __launch_bounds__(256) void pesum_kernel(const float* __restrict__ pe, float* __restrict__ pesum){
  int h = blockIdx.x*256 + threadIdx.x;
  float acc = 0.f;
  for(int s = 0; s < Sc; ++s) acc += pe[s*Hc + h];
  pesum[h] = acc;
}

// ---------------- K1: xsp[b][q][h] = sum_{s in quarter q} x[b,s,h]  (+pesum at q==0) ----------------
__global__ __launch_bounds__(256) void xsum_kernel(const float* __restrict__ x, const float* __restrict__ pesum,
                                                   float* __restrict__ xsp){
  int b = blockIdx.x;
  int q = blockIdx.y;
  int t = threadIdx.x;
  const float4* xr = (const float4*)(x + (size_t)b*Sc*Hc);
  float4 acc;
  if(q == 0) acc = ((const float4*)pesum)[t];
  else       acc = make_float4(0.f,0.f,0.f,0.f);
  int s0 = q*25;
  #pragma unroll 5
  for(int s = s0; s < s0+25; ++s){
    float4 v = xr[s*(Hc/4) + t];
    acc.x += v.x; acc.y += v.y; acc.z += v.z; acc.w += v.w;
  }
  ((float4*)(xsp + ((size_t)b*4 + q)*Hc))[t] = acc;
}

// ---------------- K1b: xs[b][h] = sum_q xsp[b][q][h] ----------------
__global__ __launch_bounds__(256) void xsred_kernel(const float* __restrict__ xsp, float* __restrict__ xs){
  int b = blockIdx.x, t = threadIdx.x;
  const float4* p = (const float4*)(xsp + (size_t)b*4*Hc);
  float4 a = p[t], b1 = p[256+t], c = p[512+t], d = p[768+t];
  a.x += b1.x + c.x + d.x;
  a.y += b1.y + c.y + d.y;
  a.z += b1.z + c.z + d.z;
  a.w += b1.w + c.w + d.w;
  ((float4*)(xs + (size_t)b*Hc))[t] = a;
}

// ---------------- K2: Ksum4[ks][b][j] = sum_{k in slice ks} xs[b][k] * Wk[j][k] ----------------
__global__ __launch_bounds__(256) void ksum_gemm2(const float* __restrict__ xs, const float* __restrict__ Wk,
                                                  float* __restrict__ Ksum4){
  __shared__ float As[32*AS_ST];   // [kk][m]  8.7 KB
  __shared__ float Bs[32*BS_ST];   // [kk][j] 16.9 KB
  const int t = threadIdx.x;
  const int j0 = blockIdx.x*128, b0 = blockIdx.y*64, ks = blockIdx.z;
  const int ty = t>>4, tx = t&15;
  float acc[4][8];
  #pragma unroll
  for(int i = 0; i < 4; ++i)
    #pragma unroll
    for(int j = 0; j < 8; ++j) acc[i][j] = 0.f;

  for(int k0 = ks*256; k0 < ks*256 + 256; k0 += 32){
    float4 af[2], bf[4];
    #pragma unroll
    for(int i = 0; i < 2; ++i){
      int id = t + i*256; int m = id>>3, q = id&7;
      af[i] = *(const float4*)(xs + ((size_t)(b0+m)<<10) + k0 + q*4);
    }
    #pragma unroll
    for(int i = 0; i < 4; ++i){
      int id = t + i*256; int r = id>>3, c = id&7;
      bf[i] = *(const float4*)(Wk + ((size_t)(j0+r)<<10) + k0 + c*4);
    }
    __syncthreads();
    #pragma unroll
    for(int i = 0; i < 2; ++i){
      int id = t + i*256; int m = id>>3, q = id&7;
      As[(q*4+0)*AS_ST + m] = af[i].x;
      As[(q*4+1)*AS_ST + m] = af[i].y;
      As[(q*4+2)*AS_ST + m] = af[i].z;
      As[(q*4+3)*AS_ST + m] = af[i].w;
    }
    #pragma unroll
    for(int i = 0; i < 4; ++i){
      int id = t + i*256; int r = id>>3, c = id&7;
      Bs[(c*4+0)*BS_ST + r] = bf[i].x;
      Bs[(c*4+1)*BS_ST + r] = bf[i].y;
      Bs[(c*4+2)*BS_ST + r] = bf[i].z;
      Bs[(c*4+3)*BS_ST + r] = bf[i].w;
    }
    __syncthreads();
    #pragma unroll 8
    for(int kk = 0; kk < 32; ++kk){
      float4 a4 = *(const float4*)&As[kk*AS_ST + ty*4];
      float4 bu = *(const float4*)&Bs[kk*BS_ST + tx*4];
      float4 bv = *(const float4*)&Bs[kk*BS_ST + 64 + tx*4];
      float a[4] = {a4.x, a4.y, a4.z, a4.w};
      float bb[8] = {bu.x,bu.y,bu.z,bu.w, bv.x,bv.y,bv.z,bv.w};
      #pragma unroll
      for(int i = 0; i < 4; ++i)
        #pragma unroll
        for(int j = 0; j < 8; ++j)
          acc[i][j] = fmaf(a[i], bb[j], acc[i][j]);
    }
  }
  #pragma unroll
  for(int i = 0; i < 4; ++i){
    float* cp = Ksum4 + (((size_t)ks*Bc + b0 + ty*4 + i)<<10) + j0 + tx*4;
    *(float4*)cp        = make_float4(acc[i][0],acc[i][1],acc[i][2],acc[i][3]);
    *(float4*)(cp + 64) = make_float4(acc[i][4],acc[i][5],acc[i][6],acc[i][7]);
  }
}

// ---------------- K2b: Ksum[b][j] = sum_ks Ksum4[ks][b][j] ----------------
__global__ __launch_bounds__(256) void ksred_kernel(const float* __restrict__ Ksum4, float* __restrict__ Ksum){
  int b = blockIdx.x, t = threadIdx.x;
  const float4* p = (const float4*)(Ksum4 + ((size_t)b<<10));
  const size_t sl = (size_t)Bc*Hc/4;
  float4 a = p[t], b1 = p[sl+t], c = p[2*sl+t], d = p[3*sl+t];
  a.x += b1.x + c.x + d.x;
  a.y += b1.y + c.y + d.y;
  a.z += b1.z + c.z + d.z;
  a.w += b1.w + c.w + d.w;
  ((float4*)(Ksum + ((size_t)b<<10)))[t] = a;
}

// ---------------- K3: v[b][n][h] = sum_a Ksum[b][n*A+a] * Wq[n*A+a][h] ----------------
__global__ __launch_bounds__(256) void v_gemm2(const float* __restrict__ Ksum, const float* __restrict__ Wq,
                                               float* __restrict__ v){
  __shared__ float As[32*AS_ST];
  __shared__ float Bs[32*BS_ST];
  const int t = threadIdx.x;
  const int h0 = blockIdx.x*128, b0 = blockIdx.y*64, n = blockIdx.z;
  const int ty = t>>4, tx = t&15;
  float acc[4][8];
  #pragma unroll
  for(int i = 0; i < 4; ++i)
    #pragma unroll
    for(int j = 0; j < 8; ++j) acc[i][j] = 0.f;

  for(int k0 = 0; k0 < Ac; k0 += 32){
    float4 af[2], bf[4];
    #pragma unroll
    for(int i = 0; i < 2; ++i){
      int id = t + i*256; int m = id>>3, q = id&7;
      af[i] = *(const float4*)(Ksum + ((size_t)(b0+m)<<10) + n*Ac + k0 + q*4);
    }
    #pragma unroll
    for(int i = 0; i < 4; ++i){
      int id = t + i*256; int kk = id>>5, q = id&31;
      bf[i] = *(const float4*)(Wq + ((size_t)(n*Ac + k0 + kk)<<10) + h0 + q*4);
    }
    __syncthreads();
    #pragma unroll
    for(int i = 0; i < 2; ++i){
      int id = t + i*256; int m = id>>3, q = id&7;
      As[(q*4+0)*AS_ST + m] = af[i].x;
      As[(q*4+1)*AS_ST + m] = af[i].y;
      As[(q*4+2)*AS_ST + m] = af[i].z;
      As[(q*4+3)*AS_ST + m] = af[i].w;
    }
    #pragma unroll
    for(int i = 0; i < 4; ++i){
      int id = t + i*256; int kk = id>>5, q = id&31;
      *(float4*)&Bs[kk*BS_ST + q*4] = bf[i];
    }
    __syncthreads();
    #pragma unroll 8
    for(int kk = 0; kk < 32; ++kk){
      float4 a4 = *(const float4*)&As[kk*AS_ST + ty*4];
      float4 bu = *(const float4*)&Bs[kk*BS_ST + tx*4];
      float4 bv = *(const float4*)&Bs[kk*BS_ST + 64 + tx*4];
      float a[4] = {a4.x, a4.y, a4.z, a4.w};
      float bb[8] = {bu.x,bu.y,bu.z,bu.w, bv.x,bv.y,bv.z,bv.w};
      #pragma unroll
      for(int i = 0; i < 4; ++i)
        #pragma unroll
        for(int j = 0; j < 8; ++j)
          acc[i][j] = fmaf(a[i], bb[j], acc[i][j]);
    }
  }
  #pragma unroll
  for(int i = 0; i < 4; ++i){
    float* cp = v + (((size_t)(b0 + ty*4 + i)*Nc + n)<<10) + h0 + tx*4;
    *(float4*)cp        = make_float4(acc[i][0],acc[i][1],acc[i][2],acc[i][3]);
    *(float4*)(cp + 64) = make_float4(acc[i][4],acc[i][5],acc[i][6],acc[i][7]);
  }
}

// ---------------- K4: x.v logits -> +gumbel -> argmax_s -> gather rows of x ----------------
// One block (1024 thr = 16 waves) per b. Wave = (kh, s-slot): each wave holds the
// kh-HALF of v[b] in regs (vr[8][2] = 64 VGPR, fits 4 waves/SIMD at <=128 VGPR).
// x read exactly once, coalesced, no LDS tile, barrier-free hot loop. Per s:
// 4 loads + 64 FMA + 34-op butterfly -> per-head k-half partial into 7KB LDS.
__global__ __launch_bounds__(1024) void attn_kernel(const float* __restrict__ x, const float* __restrict__ pe,
                                                    const float* __restrict__ v, const float* __restrict__ g,
                                                    float* __restrict__ out){
  __shared__ float part[2][Sc][9];     // [k-half][s][n] pad 9 -> conflict-light
  __shared__ int sidx[Nc];
  const int b = blockIdx.x;
  const int t = threadIdx.x;
  const int lane = t & 63;
  const int w = t >> 6;                // 0..15
  const int kh = w & 1, sw = w >> 1;   // k-half, s-slot

  // resident v half: vr[n][i] covers k = (kh*128 + i*64 + lane)*4 .. +3
  const float4* vb4 = (const float4*)(v + (size_t)b*Nc*Hc);
  float4 vr[Nc][2];
  #pragma unroll
  for(int n = 0; n < Nc; ++n)
    #pragma unroll
    for(int i = 0; i < 2; ++i)
      vr[n][i] = vb4[n*256 + kh*128 + i*64 + lane];

  const float4* xb4 = (const float4*)(x + (size_t)b*Sc*Hc);
  const float4* pe4 = (const float4*)pe;

  for(int s = sw; s < Sc; s += 8){
    float4 e[2];
    #pragma unroll
    for(int i = 0; i < 2; ++i){
      float4 xv = xb4[s*256 + kh*128 + i*64 + lane];
      float4 pv = pe4[s*256 + kh*128 + i*64 + lane];
      e[i] = make_float4(xv.x+pv.x, xv.y+pv.y, xv.z+pv.z, xv.w+pv.w);
    }
    float acc[Nc];
    #pragma unroll
    for(int n = 0; n < Nc; ++n){
      float a = 0.f;
      #pragma unroll
      for(int i = 0; i < 2; ++i){
        a = fmaf(e[i].x, vr[n][i].x, a);
        a = fmaf(e[i].y, vr[n][i].y, a);
        a = fmaf(e[i].z, vr[n][i].z, a);
        a = fmaf(e[i].w, vr[n][i].w, a);
      }
      acc[n] = a;
    }
    // stage A: butterfly within 8-lane groups, all 8 heads (24 shfl)
    #pragma unroll
    for(int m = 1; m <= 4; m <<= 1)
      #pragma unroll
      for(int n = 0; n < Nc; ++n)
        acc[n] += __shfl_xor(acc[n], m, 64);
    // select head n = lane&7 (7 cndmask)
    float keep = acc[0];
    #pragma unroll
    for(int n = 1; n < Nc; ++n)
      keep = ((lane & 7) == n) ? acc[n] : keep;
    // stage B: butterfly across groups (3 shfl)
    #pragma unroll
    for(int m = 8; m <= 32; m <<= 1)
      keep += __shfl_xor(keep, m, 64);
    if(lane < Nc) part[kh][s][lane] = keep;   // k-half partial, head = lane
  }
  __syncthreads();

  // phase 2: y = (sum of halves)/3200 + gumbel; argmax over s. Waves 0..7, one head each.
  if(w < Nc){
    int n = w, j = lane;
    float best = -FLT_MAX; int bidx = 0;
    #pragma unroll
    for(int i = 0; i < 2; ++i){
      int s2 = j + 64*i;
      if(s2 < Sc){
        float dot = part[0][s2][n] + part[1][s2][n];
        float y = dot/3200.0f + g[(size_t)(b*Nc + n)*Sc + s2];
        if(y > best){ best = y; bidx = s2; }   // strict > keeps first index (jnp tie rule)
      }
    }
    #pragma unroll
    for(int m = 32; m >= 1; m >>= 1){
      float ob = __shfl_xor(best, m, 64);
      int   oi = __shfl_xor(bidx, m, 64);
      if(ob > best || (ob == best && oi < bidx)){ best = ob; bidx = oi; }
    }
    if(j == 0) sidx[n] = bidx;
  }
  __syncthreads();

  // phase 3: out[b,n,:] = x[b, s*, :]  (2048 float4 over 1024 threads)
  float4* ob4 = (float4*)(out + (size_t)b*Nc*Hc);
  #pragma unroll
  for(int i = 0; i < 2; ++i){
    int idx = i*1024 + t;
    int nn = idx >> 8, c = idx & 255;
    ob4[idx] = xb4[sidx[nn]*256 + c];
  }
}

extern "C" void kernel_launch(void* const* d_in, const int* in_sizes, int n_in,
                              void* d_out, int out_size, void* d_ws, size_t ws_size,
                              hipStream_t stream) {
  const float* x  = (const float*)d_in[0];   // [512,100,1024]
  const float* Wq = (const float*)d_in[1];   // [1024,1024]
  const float* Wk = (const float*)d_in[2];   // [1024,1024]
  const float* g  = (const float*)d_in[3];   // [4096,100]
  float* out = (float*)d_out;                // [512,8,1024]

  char* ws = (char*)d_ws;
  float* pe    = (float*)(ws);                //    409,600 B
  float* pesum = (float*)(ws +    409600);    //      4,096 B
  float* xsp   = (float*)(ws +    413696);    //  8,388,608 B  [512][4][1024]
  float* Ksum4 = (float*)(ws +    413696);    //  aliases xsp (dead after xsred) [4][512][1024]
  float* xs    = (float*)(ws +   8802304);    //  2,097,152 B  [512][1024]
  float* Ksum  = (float*)(ws +  10899456);    //  2,097,152 B  [512][1024]
  float* v     = (float*)(ws +  12996608);    // 16,777,216 B  (total ~29.8 MB)

  pe_kernel   <<<100, 256, 0, stream>>>(pe);
  pesum_kernel<<<4,   256, 0, stream>>>(pe, pesum);
  xsum_kernel <<<dim3(512,4), 256, 0, stream>>>(x, pesum, xsp);
  xsred_kernel<<<512, 256, 0, stream>>>(xsp, xs);
  ksum_gemm2  <<<dim3(8,8,4), 256, 0, stream>>>(xs, Wk, Ksum4);
  ksred_kernel<<<512, 256, 0, stream>>>(Ksum4, Ksum);
  v_gemm2     <<<dim3(8,8,8), 256, 0, stream>>>(Ksum, Wq, v);
  attn_kernel <<<512, 1024, 0, stream>>>(x, pe, v, g, out);
}

// Round 9
// 146.242 us; speedup vs baseline: 2.7938x; 1.0470x over previous
//
#include <hip/hip_runtime.h>
#include <float.h>
#include <math.h>

#define Bc 512
#define Sc 100
#define Hc 1024
#define Ac 128
#define Nc 8
#define AS_ST 68
#define BS_ST 132

// ---------------- K0a: positional-encoding table pe[S][H] ----------------
__global__ __launch_bounds__(256) void pe_kernel(float* __restrict__ pe){
  int s = blockIdx.x;
  int t = threadIdx.x;
  const float fac = (float)(-9.210340371976184 / 1024.0);  // -ln(10000)/H
  for(int i = t; i < Hc/2; i += 256){
    float div = expf((float)(2*i) * fac);
    float a = (float)s * div;
    pe[s*Hc + 2*i]     = sinf(a);
    pe[s*Hc + 2*i + 1] = cosf(a);
  }
}

// ---------------- K0b: pesum[h] = sum_s pe[s][h] ----------------
__global__ __launch_bounds__(256) void pesum_kernel(const float* __restrict__ pe, float* __restrict__ pesum){
  int h = blockIdx.x*256 + threadIdx.x;
  float acc = 0.f;
  for(int s = 0; s < Sc; ++s) acc += pe[s*Hc + h];
  pesum[h] = acc;
}

// ---------------- K1: xsp[b][q][h] = sum_{s in quarter q} x[b,s,h]  (+pesum at q==0) ----------------
__global__ __launch_bounds__(256) void xsum_kernel(const float* __restrict__ x, const float* __restrict__ pesum,
                                                   float* __restrict__ xsp){
  int b = blockIdx.x;
  int q = blockIdx.y;
  int t = threadIdx.x;
  const float4* xr = (const float4*)(x + (size_t)b*Sc*Hc);
  float4 acc;
  if(q == 0) acc = ((const float4*)pesum)[t];
  else       acc = make_float4(0.f,0.f,0.f,0.f);
  int s0 = q*25;
  #pragma unroll 5
  for(int s = s0; s < s0+25; ++s){
    float4 v = xr[s*(Hc/4) + t];
    acc.x += v.x; acc.y += v.y; acc.z += v.z; acc.w += v.w;
  }
  ((float4*)(xsp + ((size_t)b*4 + q)*Hc))[t] = acc;
}

// ---------------- K1b: xs[b][h] = sum_q xsp[b][q][h] ----------------
__global__ __launch_bounds__(256) void xsred_kernel(const float* __restrict__ xsp, float* __restrict__ xs){
  int b = blockIdx.x, t = threadIdx.x;
  const float4* p = (const float4*)(xsp + (size_t)b*4*Hc);
  float4 a = p[t], b1 = p[256+t], c = p[512+t], d = p[768+t];
  a.x += b1.x + c.x + d.x;
  a.y += b1.y + c.y + d.y;
  a.z += b1.z + c.z + d.z;
  a.w += b1.w + c.w + d.w;
  ((float4*)(xs + (size_t)b*Hc))[t] = a;
}

// ---------------- K2: Ksum8[ks][b][j] = sum_{k in slice ks(128)} xs[b][k] * Wk[j][k] ----------------
// 64x128 tile, 4x8 frag, k-split 8 (512 blocks = 2/CU). Software-pipelined staging:
// next chunk's global loads issue after LDS write, before compute barrier (T14).
__global__ __launch_bounds__(256) void ksum_gemm2(const float* __restrict__ xs, const float* __restrict__ Wk,
                                                  float* __restrict__ Ksum8){
  __shared__ float As[32*AS_ST];   // [kk][m]  8.7 KB
  __shared__ float Bs[32*BS_ST];   // [kk][j] 16.9 KB
  const int t = threadIdx.x;
  const int j0 = blockIdx.x*128, b0 = blockIdx.y*64, ks = blockIdx.z;
  const int ty = t>>4, tx = t&15;
  float acc[4][8];
  #pragma unroll
  for(int i = 0; i < 4; ++i)
    #pragma unroll
    for(int j = 0; j < 8; ++j) acc[i][j] = 0.f;

  const int kb = ks*128;
  float4 af[2], bf[4], afn[2], bfn[4];
  #pragma unroll
  for(int i = 0; i < 2; ++i){
    int id = t + i*256; int m = id>>3, q = id&7;
    af[i] = *(const float4*)(xs + ((size_t)(b0+m)<<10) + kb + q*4);
  }
  #pragma unroll
  for(int i = 0; i < 4; ++i){
    int id = t + i*256; int r = id>>3, c = id&7;
    bf[i] = *(const float4*)(Wk + ((size_t)(j0+r)<<10) + kb + c*4);
  }

  for(int c0 = 0; c0 < 4; ++c0){
    __syncthreads();                 // previous chunk's LDS reads complete
    #pragma unroll
    for(int i = 0; i < 2; ++i){
      int id = t + i*256; int m = id>>3, q = id&7;
      As[(q*4+0)*AS_ST + m] = af[i].x;
      As[(q*4+1)*AS_ST + m] = af[i].y;
      As[(q*4+2)*AS_ST + m] = af[i].z;
      As[(q*4+3)*AS_ST + m] = af[i].w;
    }
    #pragma unroll
    for(int i = 0; i < 4; ++i){
      int id = t + i*256; int r = id>>3, c = id&7;
      Bs[(c*4+0)*BS_ST + r] = bf[i].x;
      Bs[(c*4+1)*BS_ST + r] = bf[i].y;
      Bs[(c*4+2)*BS_ST + r] = bf[i].z;
      Bs[(c*4+3)*BS_ST + r] = bf[i].w;
    }
    if(c0 < 3){                      // prefetch next chunk; in flight during compute
      int k0 = kb + (c0+1)*32;
      #pragma unroll
      for(int i = 0; i < 2; ++i){
        int id = t + i*256; int m = id>>3, q = id&7;
        afn[i] = *(const float4*)(xs + ((size_t)(b0+m)<<10) + k0 + q*4);
      }
      #pragma unroll
      for(int i = 0; i < 4; ++i){
        int id = t + i*256; int r = id>>3, c = id&7;
        bfn[i] = *(const float4*)(Wk + ((size_t)(j0+r)<<10) + k0 + c*4);
      }
    }
    __syncthreads();                 // chunk staged
    #pragma unroll 8
    for(int kk = 0; kk < 32; ++kk){
      float4 a4 = *(const float4*)&As[kk*AS_ST + ty*4];
      float4 bu = *(const float4*)&Bs[kk*BS_ST + tx*4];
      float4 bv = *(const float4*)&Bs[kk*BS_ST + 64 + tx*4];
      float a[4] = {a4.x, a4.y, a4.z, a4.w};
      float bb[8] = {bu.x,bu.y,bu.z,bu.w, bv.x,bv.y,bv.z,bv.w};
      #pragma unroll
      for(int i = 0; i < 4; ++i)
        #pragma unroll
        for(int j = 0; j < 8; ++j)
          acc[i][j] = fmaf(a[i], bb[j], acc[i][j]);
    }
    af[0]=afn[0]; af[1]=afn[1];
    bf[0]=bfn[0]; bf[1]=bfn[1]; bf[2]=bfn[2]; bf[3]=bfn[3];
  }
  #pragma unroll
  for(int i = 0; i < 4; ++i){
    float* cp = Ksum8 + (((size_t)ks*Bc + b0 + ty*4 + i)<<10) + j0 + tx*4;
    *(float4*)cp        = make_float4(acc[i][0],acc[i][1],acc[i][2],acc[i][3]);
    *(float4*)(cp + 64) = make_float4(acc[i][4],acc[i][5],acc[i][6],acc[i][7]);
  }
}

// ---------------- K2b: Ksum[b][j] = sum_ks Ksum8[ks][b][j] ----------------
__global__ __launch_bounds__(256) void ksred8_kernel(const float* __restrict__ Ksum8, float* __restrict__ Ksum){
  int b = blockIdx.x, t = threadIdx.x;
  const float4* p = (const float4*)(Ksum8 + ((size_t)b<<10));
  const size_t sl = (size_t)Bc*Hc/4;
  float4 a = p[t];
  #pragma unroll
  for(int i = 1; i < 8; ++i){
    float4 q = p[i*sl + t];
    a.x += q.x; a.y += q.y; a.z += q.z; a.w += q.w;
  }
  ((float4*)(Ksum + ((size_t)b<<10)))[t] = a;
}

// ---------------- K3: v[b][n][h] = sum_a Ksum[b][n*A+a] * Wq[n*A+a][h] ----------------
// Same 64x128 / 4x8 structure, software-pipelined staging.
__global__ __launch_bounds__(256) void v_gemm2(const float* __restrict__ Ksum, const float* __restrict__ Wq,
                                               float* __restrict__ v){
  __shared__ float As[32*AS_ST];
  __shared__ float Bs[32*BS_ST];
  const int t = threadIdx.x;
  const int h0 = blockIdx.x*128, b0 = blockIdx.y*64, n = blockIdx.z;
  const int ty = t>>4, tx = t&15;
  float acc[4][8];
  #pragma unroll
  for(int i = 0; i < 4; ++i)
    #pragma unroll
    for(int j = 0; j < 8; ++j) acc[i][j] = 0.f;

  float4 af[2], bf[4], afn[2], bfn[4];
  #pragma unroll
  for(int i = 0; i < 2; ++i){
    int id = t + i*256; int m = id>>3, q = id&7;
    af[i] = *(const float4*)(Ksum + ((size_t)(b0+m)<<10) + n*Ac + q*4);
  }
  #pragma unroll
  for(int i = 0; i < 4; ++i){
    int id = t + i*256; int kk = id>>5, q = id&31;
    bf[i] = *(const float4*)(Wq + ((size_t)(n*Ac + kk)<<10) + h0 + q*4);
  }

  for(int c0 = 0; c0 < 4; ++c0){
    __syncthreads();
    #pragma unroll
    for(int i = 0; i < 2; ++i){
      int id = t + i*256; int m = id>>3, q = id&7;
      As[(q*4+0)*AS_ST + m] = af[i].x;
      As[(q*4+1)*AS_ST + m] = af[i].y;
      As[(q*4+2)*AS_ST + m] = af[i].z;
      As[(q*4+3)*AS_ST + m] = af[i].w;
    }
    #pragma unroll
    for(int i = 0; i < 4; ++i){
      int id = t + i*256; int kk = id>>5, q = id&31;
      *(float4*)&Bs[kk*BS_ST + q*4] = bf[i];
    }
    if(c0 < 3){
      int k0 = (c0+1)*32;
      #pragma unroll
      for(int i = 0; i < 2; ++i){
        int id = t + i*256; int m = id>>3, q = id&7;
        afn[i] = *(const float4*)(Ksum + ((size_t)(b0+m)<<10) + n*Ac + k0 + q*4);
      }
      #pragma unroll
      for(int i = 0; i < 4; ++i){
        int id = t + i*256; int kk = id>>5, q = id&31;
        bfn[i] = *(const float4*)(Wq + ((size_t)(n*Ac + k0 + kk)<<10) + h0 + q*4);
      }
    }
    __syncthreads();
    #pragma unroll 8
    for(int kk = 0; kk < 32; ++kk){
      float4 a4 = *(const float4*)&As[kk*AS_ST + ty*4];
      float4 bu = *(const float4*)&Bs[kk*BS_ST + tx*4];
      float4 bv = *(const float4*)&Bs[kk*BS_ST + 64 + tx*4];
      float a[4] = {a4.x, a4.y, a4.z, a4.w};
      float bb[8] = {bu.x,bu.y,bu.z,bu.w, bv.x,bv.y,bv.z,bv.w};
      #pragma unroll
      for(int i = 0; i < 4; ++i)
        #pragma unroll
        for(int j = 0; j < 8; ++j)
          acc[i][j] = fmaf(a[i], bb[j], acc[i][j]);
    }
    af[0]=afn[0]; af[1]=afn[1];
    bf[0]=bfn[0]; bf[1]=bfn[1]; bf[2]=bfn[2]; bf[3]=bfn[3];
  }
  #pragma unroll
  for(int i = 0; i < 4; ++i){
    float* cp = v + (((size_t)(b0 + ty*4 + i)*Nc + n)<<10) + h0 + tx*4;
    *(float4*)cp        = make_float4(acc[i][0],acc[i][1],acc[i][2],acc[i][3]);
    *(float4*)(cp + 64) = make_float4(acc[i][4],acc[i][5],acc[i][6],acc[i][7]);
  }
}

// ---------------- K4: x.v logits -> +gumbel -> argmax_s -> gather rows of x ----------------
// Round-4 attn (best proven): 1024 thr/block, LDS x-tile with XOR swizzle, lanes->s,
// k wave-split 8 ways, per-k-eighth v loads from global (L2-resident).
__global__ __launch_bounds__(1024) void attn_kernel(const float* __restrict__ x, const float* __restrict__ pe,
                                                    const float* __restrict__ v, const float* __restrict__ g,
                                                    float* __restrict__ out){
  __shared__ float4 tile[1600];        // [r<100][16 slots], 16B-slot XOR swizzle, 25.6 KB
  __shared__ float part[8][Nc][104];   // [kq][n][s] 26.6 KB
  __shared__ int sidx[Nc];
  const int b = blockIdx.x;
  const int t = threadIdx.x;
  const int lane = t & 63;
  const int w  = __builtin_amdgcn_readfirstlane(t >> 6);  // wave id 0..15
  const int kq = w & 7, sh = w >> 3;

  const int r1 = t >> 4, c1 = t & 15;
  const bool has2 = (t < 576);
  const int e2 = t + 1024;
  const int r2 = e2 >> 4, c2 = e2 & 15;

  const float* xb = x + (size_t)b*Sc*Hc;
  const float* vb = v + (size_t)b*Nc*Hc;

  int rw = sh*64 + lane;               // 0..127
  int r  = (rw < Sc) ? rw : (Sc-1);
  const bool valid = (rw < Sc);

  float acc[Nc];
  #pragma unroll
  for(int n = 0; n < Nc; ++n) acc[n] = 0.f;

  float4 xv1 = *(const float4*)(xb + r1*Hc + c1*4);
  float4 pv1 = *(const float4*)(pe + r1*Hc + c1*4);
  float4 xv2 = make_float4(0,0,0,0), pv2 = make_float4(0,0,0,0);
  if(has2){ xv2 = *(const float4*)(xb + r2*Hc + c2*4);
            pv2 = *(const float4*)(pe + r2*Hc + c2*4); }

  for(int kt = 0; kt < 16; ++kt){
    __syncthreads();
    tile[r1*16 + (c1 ^ (r1&7))] = make_float4(xv1.x+pv1.x, xv1.y+pv1.y, xv1.z+pv1.z, xv1.w+pv1.w);
    if(has2)
      tile[r2*16 + (c2 ^ (r2&7))] = make_float4(xv2.x+pv2.x, xv2.y+pv2.y, xv2.z+pv2.z, xv2.w+pv2.w);
    if(kt < 15){
      int ko = (kt+1)*64;
      xv1 = *(const float4*)(xb + r1*Hc + ko + c1*4);
      pv1 = *(const float4*)(pe + r1*Hc + ko + c1*4);
      if(has2){ xv2 = *(const float4*)(xb + r2*Hc + ko + c2*4);
                pv2 = *(const float4*)(pe + r2*Hc + ko + c2*4); }
    }
    __syncthreads();
    #pragma unroll
    for(int j = 0; j < 2; ++j){
      float4 xe = tile[r*16 + ((kq*2 + j) ^ (r&7))];
      const float* vk = vb + kt*64 + kq*8 + j*4;
      #pragma unroll
      for(int n = 0; n < Nc; ++n){
        const float* vn = vk + n*Hc;
        acc[n] = fmaf(xe.x, vn[0], acc[n]);
        acc[n] = fmaf(xe.y, vn[1], acc[n]);
        acc[n] = fmaf(xe.z, vn[2], acc[n]);
        acc[n] = fmaf(xe.w, vn[3], acc[n]);
      }
    }
  }
  if(valid){
    #pragma unroll
    for(int n = 0; n < Nc; ++n) part[kq][n][rw] = acc[n];
  }
  __syncthreads();

  if(w < Nc){
    int n = w, j = lane;
    float best = -FLT_MAX; int bidx = 0;
    #pragma unroll
    for(int i = 0; i < 2; ++i){
      int s2 = j + 64*i;
      if(s2 < Sc){
        float dot = 0.f;
        #pragma unroll
        for(int q = 0; q < 8; ++q) dot += part[q][n][s2];
        float y = dot/3200.0f + g[(size_t)(b*Nc + n)*Sc + s2];
        if(y > best){ best = y; bidx = s2; }   // strict > keeps first index (jnp tie rule)
      }
    }
    #pragma unroll
    for(int m = 32; m >= 1; m >>= 1){
      float ob = __shfl_xor(best, m, 64);
      int   oi = __shfl_xor(bidx, m, 64);
      if(ob > best || (ob == best && oi < bidx)){ best = ob; bidx = oi; }
    }
    if(j == 0) sidx[n] = bidx;
  }
  __syncthreads();

  const float4* xb4 = (const float4*)xb;
  float4* ob4 = (float4*)(out + (size_t)b*Nc*Hc);
  #pragma unroll
  for(int i = 0; i < 2; ++i){
    int idx = i*1024 + t;
    int nn = idx >> 8, c = idx & 255;
    ob4[idx] = xb4[sidx[nn]*256 + c];
  }
}

extern "C" void kernel_launch(void* const* d_in, const int* in_sizes, int n_in,
                              void* d_out, int out_size, void* d_ws, size_t ws_size,
                              hipStream_t stream) {
  const float* x  = (const float*)d_in[0];   // [512,100,1024]
  const float* Wq = (const float*)d_in[1];   // [1024,1024]
  const float* Wk = (const float*)d_in[2];   // [1024,1024]
  const float* g  = (const float*)d_in[3];   // [4096,100]
  float* out = (float*)d_out;                // [512,8,1024]

  char* ws = (char*)d_ws;
  // liveness-based aliasing: v overwrites xsp/xs/low-Ksum8 (all dead by v_gemm2).
  float* pe    = (float*)(ws);                //    409,600 B
  float* pesum = (float*)(ws +    409600);    //      4,096 B
  float* xsp   = (float*)(ws +    413696);    //  8,388,608 B  [512][4][1024]
  float* xs    = (float*)(ws +   8802304);    //  2,097,152 B  [512][1024]
  float* Ksum8 = (float*)(ws +  10899456);    // 16,777,216 B  [8][512][1024]
  float* Ksum  = (float*)(ws +  27676672);    //  2,097,152 B  [512][1024]
  float* v     = (float*)(ws +    413696);    // 16,777,216 B  alias (ends 17,190,912 < 27,676,672)
                                              // total 29,773,824 B (proven size)

  pe_kernel    <<<100, 256, 0, stream>>>(pe);
  pesum_kernel <<<4,   256, 0, stream>>>(pe, pesum);
  xsum_kernel  <<<dim3(512,4), 256, 0, stream>>>(x, pesum, xsp);
  xsred_kernel <<<512, 256, 0, stream>>>(xsp, xs);
  ksum_gemm2   <<<dim3(8,8,8), 256, 0, stream>>>(xs, Wk, Ksum8);
  ksred8_kernel<<<512, 256, 0, stream>>>(Ksum8, Ksum);
  v_gemm2      <<<dim3(8,8,8), 256, 0, stream>>>(Ksum, Wq, v);
  attn_kernel  <<<512, 1024, 0, stream>>>(x, pe, v, g, out);
}